// Round 4
// baseline (913.390 us; speedup 1.0000x reference)
//
#include <hip/hip_runtime.h>
#include <hip/hip_bf16.h>

// x: [B=1024, N=65536] f32, index: [N] i32 permutation, group size 64.
#define BATCH   1024
#define NEUR    65536
#define NGRP    1024                  // NEUR / 64 groups
#define BLK     1024                  // threads per block (16 waves)
#define F4_PER_ROW (NEUR / 4)         // 16384 float4 per row
#define ITERS   (F4_PER_ROW / BLK)    // 16 float4 per thread
#define WAVES   (BLK / 64)            // 16
#define GRP_PER_WAVE (NGRP / WAVES)   // 64

// Build inverse permutation -> group id table: group_of[index[i]] = i / 64.
// Pure scatter of a permutation: race-free, no atomics.
__global__ void build_group_of(const int* __restrict__ index,
                               int* __restrict__ group_of) {
    int i = blockIdx.x * blockDim.x + threadIdx.x;
    if (i < NEUR) group_of[index[i]] = i >> 6;
}

// One block per batch row. NO ATOMICS (R3 lesson: 67M ds_add lane-ops at
// ~3.5 cy/op serialized on the LDS pipe WAS the 383 us).
//   phase 1 (permuted domain): wave w owns groups [w*64, w*64+64); lane j
//     loads index[g*64+j] (coalesced) then xrow[idx] (4B gather, L2-cached
//     for phase 2 reuse); butterfly shfl reduce; lane 0 writes 1/sum to LDS.
//   phase 2 (original domain): coalesced float4 re-read (L2-hot), scale by
//     rsum[group_of[n]], coalesced float4 store.
__global__ __launch_bounds__(BLK, 8)
void lateral_norm_kernel(const float* __restrict__ x,
                         const int* __restrict__ index,
                         const int* __restrict__ group_of,
                         float* __restrict__ out) {
    __shared__ float rsum[NGRP];       // 4 KB

    const int b    = blockIdx.x;
    const int t    = threadIdx.x;
    const int wave = t >> 6;
    const int lane = t & 63;

    const float* __restrict__ xrow = x + (size_t)b * NEUR;

    // Phase 1: wave-per-group gather + shuffle reduction. 64 groups per wave.
    #pragma unroll 4
    for (int i = 0; i < GRP_PER_WAVE; ++i) {
        const int g   = wave * GRP_PER_WAVE + i;
        const int idx = index[g * 64 + lane];   // coalesced 256B (L2-resident)
        float v = xrow[idx];                    // random 4B gather, fills L2
        v += __shfl_xor(v, 1,  64);
        v += __shfl_xor(v, 2,  64);
        v += __shfl_xor(v, 4,  64);
        v += __shfl_xor(v, 8,  64);
        v += __shfl_xor(v, 16, 64);
        v += __shfl_xor(v, 32, 64);
        if (lane == 0) rsum[g] = 1.0f / v;
    }
    __syncthreads();

    const int4* __restrict__ gof  = (const int4*)group_of;
    float4*     __restrict__ orow = (float4*)(out + (size_t)b * NEUR);
    const float4* __restrict__ xrow4 = (const float4*)xrow;

    // Phase 2: coalesced stream (row is L2-hot from the phase-1 gather).
    #pragma unroll
    for (int it = 0; it < ITERS; ++it) {
        const int e = it * BLK + t;
        const float4 v = xrow4[e];
        const int4 g4 = gof[e];        // 256 KB table, L2-resident
        float4 o;
        o.x = v.x * rsum[g4.x];
        o.y = v.y * rsum[g4.y];
        o.z = v.z * rsum[g4.z];
        o.w = v.w * rsum[g4.w];
        orow[e] = o;
    }
}

extern "C" void kernel_launch(void* const* d_in, const int* in_sizes, int n_in,
                              void* d_out, int out_size, void* d_ws, size_t ws_size,
                              hipStream_t stream) {
    const float* x     = (const float*)d_in[0];
    const int*   index = (const int*)d_in[1];
    float*       out   = (float*)d_out;

    int* group_of = (int*)d_ws;        // 256 KB scratch

    build_group_of<<<(NEUR + 255) / 256, 256, 0, stream>>>(index, group_of);
    lateral_norm_kernel<<<BATCH, BLK, 0, stream>>>(x, index, group_of, out);
}

// Round 5
// 212.267 us; speedup vs baseline: 4.3030x; 4.3030x over previous
//
#include <hip/hip_runtime.h>
#include <hip/hip_bf16.h>

// x: [B=1024, N=65536] f32, index: [N] i32 permutation, group size 64.
#define BATCH   1024
#define NEUR    65536
#define NGRP    1024                  // groups (== BLK, thread t owns group t)
#define BLK     1024
#define NCHUNK  8
#define CHUNK   (NEUR / NCHUNK)       // 8192 floats staged per LDS chunk (32 KB)
#define CHUNK_F4 (CHUNK / 4)          // 2048 float4
#define KMAX    64                    // hard upper bound: a whole group in one chunk
#define ROW_F4  (NEUR / 4)            // 16384
#define C_ITERS (ROW_F4 / BLK)        // 16

// ws layout: [group_of: 64K ints][counts: 8K ints][bucket: 8*64*1024 ushort]
//            256 KB            + 32 KB          + 1 MB  = ~1.3 MB

// Prep (no atomics, fully deterministic): wave == one group (64 consecutive
// permuted positions). Ballot/popcount computes each member's slot within its
// source-chunk bucket. Also builds group_of (inverse permutation -> group).
__global__ void build_tables(const int* __restrict__ index,
                             int* __restrict__ group_of,
                             int* __restrict__ counts,
                             unsigned short* __restrict__ bucket) {
    const int p    = blockIdx.x * blockDim.x + threadIdx.x; // permuted position
    const int lane = threadIdx.x & 63;
    const int g    = p >> 6;                                // group id (wave-uniform)
    const int s    = index[p];                              // source neuron
    group_of[s] = g;
    const int c = s / CHUNK;                                // source chunk 0..7
    unsigned long long mc = 0;
    #pragma unroll
    for (int cc = 0; cc < NCHUNK; ++cc) {
        unsigned long long m = __ballot(c == cc);
        if (cc == c) mc = m;
        if (lane == cc) counts[cc * NGRP + g] = __popcll(m); // lanes 0..7 write counts
    }
    const unsigned long long below = (1ull << lane) - 1ull;
    const int k = __popcll(mc & below);                     // slot within (c, g)
    if (k < KMAX)
        bucket[((c * KMAX + k) << 10) | g] = (unsigned short)(s & (CHUNK - 1));
}

// One block per batch row. No LDS atomics (R3: ~3.5cy/lane-op wall), no global
// gather (R4: 12x over-fetch). Chunk the row through LDS; thread t privately
// accumulates group t via the precomputed bucket lists (VALU adds at full rate).
__global__ __launch_bounds__(BLK, 8)
void lateral_norm_kernel(const float* __restrict__ x,
                         const int* __restrict__ group_of,
                         const int* __restrict__ counts,
                         const unsigned short* __restrict__ bucket,
                         float* __restrict__ out) {
    __shared__ float xs[CHUNK];        // 32 KB staged chunk
    __shared__ float rsum[NGRP];       // 4 KB

    const int b = blockIdx.x;
    const int t = threadIdx.x;
    const float4* __restrict__ xrow4 = (const float4*)(x + (size_t)b * NEUR);

    float acc = 0.0f;
    // T14-style reg prefetch of the next chunk while the k-loop runs.
    float4 pre0 = xrow4[t];
    float4 pre1 = xrow4[BLK + t];

    for (int c = 0; c < NCHUNK; ++c) {
        ((float4*)xs)[t]       = pre0;
        ((float4*)xs)[BLK + t] = pre1;
        if (c + 1 < NCHUNK) {
            pre0 = xrow4[(c + 1) * CHUNK_F4 + t];          // in flight during k-loop
            pre1 = xrow4[(c + 1) * CHUNK_F4 + BLK + t];
        }
        __syncthreads();
        const int cnt = counts[c * NGRP + t];              // coalesced, L2-resident
        const unsigned short* __restrict__ bk = bucket + ((size_t)(c * KMAX) << 10);
        for (int k = 0;; ++k) {
            if (!__ballot(k < cnt)) break;                 // wave-max trip count (~16)
            if (k < cnt)
                acc += xs[bk[(k << 10) | t]];              // coalesced list, random-bank LDS
        }
        __syncthreads();                                   // before overwriting xs
    }

    rsum[t] = 1.0f / acc;                                  // thread t owns group t
    __syncthreads();

    const int4* __restrict__ gof4  = (const int4*)group_of;
    float4*     __restrict__ orow4 = (float4*)(out + (size_t)b * NEUR);

    // Phase C: coalesced re-stream (L3-resident), scale, coalesced store.
    #pragma unroll
    for (int it = 0; it < C_ITERS; ++it) {
        const int e = it * BLK + t;
        const float4 v = xrow4[e];
        const int4  g = gof4[e];
        float4 o;
        o.x = v.x * rsum[g.x];
        o.y = v.y * rsum[g.y];
        o.z = v.z * rsum[g.z];
        o.w = v.w * rsum[g.w];
        orow4[e] = o;
    }
}

extern "C" void kernel_launch(void* const* d_in, const int* in_sizes, int n_in,
                              void* d_out, int out_size, void* d_ws, size_t ws_size,
                              hipStream_t stream) {
    const float* x     = (const float*)d_in[0];
    const int*   index = (const int*)d_in[1];
    float*       out   = (float*)d_out;

    int*            group_of = (int*)d_ws;                       // 256 KB
    int*            counts   = group_of + NEUR;                  // 32 KB
    unsigned short* bucket   = (unsigned short*)(counts + NCHUNK * NGRP); // 1 MB

    build_tables<<<NEUR / BLK, BLK, 0, stream>>>(index, group_of, counts, bucket);
    lateral_norm_kernel<<<BATCH, BLK, 0, stream>>>(x, group_of, counts, bucket, out);
}